// Round 5
// baseline (322.734 us; speedup 1.0000x reference)
//
#include <hip/hip_runtime.h>
#include <hip/hip_bf16.h>

#define NEG_SLOPE 0.2f
#define F1_NODES 16
#define F1_PAD 264  // row stride 528B: rows land on rotating bank groups

typedef short bf16x8 __attribute__((ext_vector_type(8)));
typedef float f32x4 __attribute__((ext_vector_type(4)));

union BF8 { bf16x8 v; __hip_bfloat16 e[8]; };
union BF4 { uint2 u; __hip_bfloat16 e[4]; };

__device__ __forceinline__ float b2f(__hip_bfloat16 b) { return __bfloat162float(b); }

__device__ __forceinline__ float loadF(const void* p, int i, bool f32) {
    return f32 ? ((const float*)p)[i] : b2f(((const __hip_bfloat16*)p)[i]);
}

__device__ __forceinline__ void getSD(const int* ei, int e, int E, bool i64, int N,
                                      int& s, int& d) {
    if (e < E) {
        if (i64) { s = ei[2 * e]; d = ei[2 * (E + e)]; }
        else     { s = ei[e];     d = ei[E + e]; }
    } else { s = e - E; d = s; }
    s = min(max(s, 0), N - 1);
    d = min(max(d, 0), N - 1);
}

// lrelu(v) = max(v, 0.2v) for slope in (0,1): 2 VALU ops, no cndmask
__device__ __forceinline__ float lrelu(float v) { return fmaxf(v, NEG_SLOPE * v); }
// exp without max-subtraction: logits ~N(0,1.5); clamp for overflow safety.
__device__ __forceinline__ float eexp(float v) { return __expf(fminf(v, 80.f)); }

__device__ __forceinline__ float bfLo(unsigned u) { return __uint_as_float(u << 16); }
__device__ __forceinline__ float bfHi(unsigned u) { return __uint_as_float(u & 0xffff0000u); }

// block 0 -> flags[0] (floats f32?); block 1 -> flags[1] (edges int64?);
// blocks 2.. zero the counts array. Deterministic writes, no pre-memset needed.
__global__ void detect_kernel(const void* x, const int* ei, int* flags,
                              int* counts, int N) {
    if (blockIdx.x == 0) {
        int bad = 0;
        for (int i = threadIdx.x; i < 8192; i += 256) {
            unsigned short u = ((const unsigned short*)x)[i];
            if (((u >> 7) & 0xFF) >= 140) bad = 1;
        }
        __shared__ int r[4];
        unsigned long long m = __ballot(bad);
        if ((threadIdx.x & 63) == 0) r[threadIdx.x >> 6] = (m != 0ull);
        __syncthreads();
        if (threadIdx.x == 0) flags[0] = (r[0] | r[1] | r[2] | r[3]) ? 1 : 0;
    } else if (blockIdx.x == 1) {
        __shared__ int cnt;
        if (threadIdx.x == 0) cnt = 0;
        __syncthreads();
        int z = 0;
        for (int i = threadIdx.x; i < 4096; i += 256)
            if (ei[2 * i + 1] == 0) ++z;
        atomicAdd(&cnt, z);
        __syncthreads();
        if (threadIdx.x == 0) flags[1] = (cnt >= 2048) ? 1 : 0;
    } else {
        int i = (blockIdx.x - 2) * 256 + threadIdx.x;
        if (i < N) counts[i] = 0;
    }
}

// merged: blocks [0,PB) transpose weights; blocks [PB,..) count in-degrees AND
// capture each edge's rank within its dst segment (atomicAdd return value).
// The rank store is coalesced, so the atomic's return latency hides easily;
// this is the ONLY atomic pass — scatter then needs no atomics at all.
// 4 edges per thread = 4 independent atomic round-trips in flight.
__global__ void prep_count_kernel(const void* __restrict__ W1,
                                  const void* __restrict__ W2,
                                  const int* __restrict__ ei,
                                  const int* __restrict__ flags,
                                  __hip_bfloat16* __restrict__ W1t,
                                  __hip_bfloat16* __restrict__ W2t,
                                  int* __restrict__ counts,
                                  int* __restrict__ rank,
                                  int E, int N, int PB) {
    if ((int)blockIdx.x < PB) {
        const bool f32 = (flags[0] != 0);
        int i = blockIdx.x * 256 + threadIdx.x;
        if (i < 256 * 128) {
            int c = i >> 7, k = i & 127;
            W1t[c * 128 + k] = __float2bfloat16(loadF(W1, k * 256 + c, f32));
        } else if (i < 256 * 128 + 64 * 256) {
            int t = i - 256 * 128, c = t >> 8, k = t & 255;
            W2t[c * 256 + k] = __float2bfloat16(loadF(W2, k * 64 + c, f32));
        }
    } else {
        const bool i64 = (flags[1] != 0);
        const int Et = E + N;
        int base = (blockIdx.x - PB) * 1024 + threadIdx.x;
#pragma unroll
        for (int j = 0; j < 4; ++j) {
            int e = base + j * 256;
            if (e < Et) {
                int s, d;
                getSD(ei, e, E, i64, N, s, d);
                rank[e] = atomicAdd(&counts[d], 1);
            }
        }
    }
}

// ---------------- CSR build ----------------

__global__ void scanA_kernel(const int* __restrict__ counts,
                             int* __restrict__ blocksum, int N) {
    int b = blockIdx.x;
    int i = b * 256 + threadIdx.x;
    int v = (i < N) ? counts[i] : 0;
    for (int off = 32; off >= 1; off >>= 1) v += __shfl_down(v, off, 64);
    __shared__ int ws[4];
    if ((threadIdx.x & 63) == 0) ws[threadIdx.x >> 6] = v;
    __syncthreads();
    if (threadIdx.x == 0) blocksum[b] = ws[0] + ws[1] + ws[2] + ws[3];
}

__global__ void scanB_kernel(const int* __restrict__ blocksum,
                             int* __restrict__ blockoff, int nb) {
    int t = threadIdx.x;  // 1024
    int own = (t < nb) ? blocksum[t] : 0;
    int v = own;
    int lane = t & 63, w = t >> 6;
    for (int d = 1; d < 64; d <<= 1) {
        int u = __shfl_up(v, d, 64);
        if (lane >= d) v += u;
    }
    __shared__ int wsum[16];
    if (lane == 63) wsum[w] = v;
    __syncthreads();
    if (w == 0 && lane < 16) {
        int s = wsum[lane];
        for (int d = 1; d < 16; d <<= 1) {
            int u = __shfl_up(s, d, 64);
            if (lane >= d) s += u;
        }
        wsum[lane] = s;
    }
    __syncthreads();
    int woff = (w > 0) ? wsum[w - 1] : 0;
    if (t < nb) blockoff[t] = woff + v - own;
}

__global__ void scanC_kernel(const int* __restrict__ counts,
                             const int* __restrict__ blockoff,
                             int* __restrict__ row_start, int N, int Et) {
    int b = blockIdx.x;
    int t = threadIdx.x;
    int i = b * 256 + t;
    int own = (i < N) ? counts[i] : 0;
    int v = own;
    int lane = t & 63, w = t >> 6;
    for (int d = 1; d < 64; d <<= 1) {
        int u = __shfl_up(v, d, 64);
        if (lane >= d) v += u;
    }
    __shared__ int ws[4];
    if (lane == 63) ws[w] = v;
    __syncthreads();
    int woff = 0;
#pragma unroll
    for (int q = 0; q < 4; ++q) woff += (q < w) ? ws[q] : 0;
    int exc = blockoff[b] + woff + v - own;
    if (i < N) row_start[i] = exc;
    if (i == N - 1) row_start[N] = Et;
}

// ---------------- scatter (CSR fill, NO atomics) merged with layer-1 GEMM ----
// position = row_start[d] + rank[e]: rank came from the count pass's atomic
// return. Loads (ei, rank) are coalesced; row_start[d] is a cached 200KB
// gather; the store is fire-and-forget. 4 edges/thread for MLP.
__global__ void scatter_gemm1_kernel(const int* __restrict__ ei, int E, int N,
                                     const int* __restrict__ flags,
                                     const int* __restrict__ rank,
                                     const int* __restrict__ row_start,
                                     int* __restrict__ csr_src,
                                     const void* __restrict__ x,
                                     const __hip_bfloat16* __restrict__ W1t,
                                     const void* __restrict__ att_src,
                                     const void* __restrict__ att_dst,
                                     __hip_bfloat16* __restrict__ h1,
                                     float* __restrict__ a_s,
                                     float* __restrict__ a_d, int SB) {
    if ((int)blockIdx.x < SB) {
        const bool i64 = (flags[1] != 0);
        const int Et = E + N;
        int base = blockIdx.x * 1024 + threadIdx.x;
#pragma unroll
        for (int j = 0; j < 4; ++j) {
            int e = base + j * 256;
            if (e < Et) {
                int s, d;
                getSD(ei, e, E, i64, N, s, d);
                csr_src[row_start[d] + rank[e]] = s;
            }
        }
        return;
    }
    const bool f32 = (flags[0] != 0);
    const int n0 = (blockIdx.x - SB) * 16;
    const int w = threadIdx.x >> 6;
    const int lane = threadIdx.x & 63;
    const int q = lane >> 4;
    const int cl = lane & 15;

    bf16x8 a[4];
    const int an = min(n0 + cl, N - 1);
    if (f32) {
        const float* xp = (const float*)x + (size_t)an * 128;
#pragma unroll
        for (int kc = 0; kc < 4; ++kc) {
            f32x4 v0 = *(const f32x4*)(xp + kc * 32 + q * 8);
            f32x4 v1 = *(const f32x4*)(xp + kc * 32 + q * 8 + 4);
            BF8 t;
#pragma unroll
            for (int i = 0; i < 4; ++i) {
                t.e[i]     = __float2bfloat16(v0[i]);
                t.e[i + 4] = __float2bfloat16(v1[i]);
            }
            a[kc] = t.v;
        }
    } else {
        const __hip_bfloat16* xp = (const __hip_bfloat16*)x + (size_t)an * 128;
#pragma unroll
        for (int kc = 0; kc < 4; ++kc)
            a[kc] = *(const bf16x8*)(xp + kc * 32 + q * 8);
    }
    f32x4 acc[4];
#pragma unroll
    for (int ct = 0; ct < 4; ++ct) acc[ct] = (f32x4){0.f, 0.f, 0.f, 0.f};
#pragma unroll
    for (int kc = 0; kc < 4; ++kc) {
#pragma unroll
        for (int ct = 0; ct < 4; ++ct) {
            int col = w * 64 + ct * 16 + cl;
            bf16x8 b = *(const bf16x8*)(W1t + (size_t)col * 128 + kc * 32 + q * 8);
            acc[ct] = __builtin_amdgcn_mfma_f32_16x16x32_bf16(a[kc], b, acc[ct], 0, 0, 0);
        }
    }
    float asw[4], adw[4];
#pragma unroll
    for (int ct = 0; ct < 4; ++ct) {
        int col = w * 64 + ct * 16 + cl;
        asw[ct] = loadF(att_src, col, f32);
        adw[ct] = loadF(att_dst, col, f32);
    }
#pragma unroll
    for (int r = 0; r < 4; ++r) {
        int n = n0 + q * 4 + r;
        if (n < N) {
#pragma unroll
            for (int ct = 0; ct < 4; ++ct)
                h1[(size_t)n * 256 + w * 64 + ct * 16 + cl] = __float2bfloat16(acc[ct][r]);
        }
        float pas = acc[0][r] * asw[0] + acc[1][r] * asw[1]
                  + acc[2][r] * asw[2] + acc[3][r] * asw[3];
        float pad = acc[0][r] * adw[0] + acc[1][r] * adw[1]
                  + acc[2][r] * adw[2] + acc[3][r] * adw[3];
#pragma unroll
        for (int m = 1; m <= 8; m <<= 1) {
            pas += __shfl_xor(pas, m, 64);
            pad += __shfl_xor(pad, m, 64);
        }
        if (cl == 0 && n < N) {
            a_s[n * 4 + w] = pas;
            a_d[n * 4 + w] = pad;
        }
    }
}

// ---------------- fused layer-1 aggregation + per-wave layer-2 GEMM ----------
// BARRIER-FREE merge (R4 post-mortem: __syncthreads coupling 4 waves cost 18µs
// of tail/occupancy). Each wave aggregates its 4 nodes into a PRIVATE 4x264
// LDS strip, then runs its own MFMA epilogue with swapped operand roles:
//   D[ch(16) x nodecol(16)] = W2slice(A, all lanes valid, global) x act(B, LDS)
// Node cols 4-15 are garbage but matmul columns are independent -> never
// stored. No __syncthreads anywhere; waves retire independently like the
// standalone fused1 (71.5µs aggregation rate).
__global__ void fused1_gemm2_kernel(const int* __restrict__ row_start,
                                    const int* __restrict__ csr_src,
                                    const float* __restrict__ a_s,
                                    const float* __restrict__ a_d,
                                    const __hip_bfloat16* __restrict__ h1,
                                    const void* __restrict__ bias1,
                                    const __hip_bfloat16* __restrict__ W2t,
                                    const void* __restrict__ att_src2,
                                    const void* __restrict__ att_dst2,
                                    const int* __restrict__ flags,
                                    __hip_bfloat16* __restrict__ h2b,
                                    float* __restrict__ a_s2,
                                    float* __restrict__ a_d2, int N) {
    const bool f32 = (flags[0] != 0);
    __shared__ __hip_bfloat16 strip[4][4][F1_PAD];  // per-wave private strips
    const int w = threadIdx.x >> 6;
    const int lane = threadIdx.x & 63;
    const int half = lane >> 5;   // which edge of the pair
    const int hl = lane & 31;     // channels hl*8 .. hl*8+7
    const int h = hl >> 3;        // head of this channel group
    const int n0 = blockIdx.x * F1_NODES;
    const int wn0 = n0 + w * 4;   // this wave's first node

    // bias for this lane's 8 channels (same for all nodes) — hoisted
    float b1v[8];
#pragma unroll
    for (int i = 0; i < 8; ++i) b1v[i] = loadF(bias1, hl * 8 + i, f32);

    for (int i = 0; i < 4; ++i) {
        const int n = wn0 + i;
        if (n >= N) break;
        int lo = row_start[n], hi = row_start[n + 1];
        float ad = a_d[n * 4 + h];
        float l = 0.f;
        float acc[8] = {0.f, 0.f, 0.f, 0.f, 0.f, 0.f, 0.f, 0.f};
        int t = lo + half;
        for (; t + 6 < hi; t += 8) {               // 4 edges per half per iter
            int s1 = csr_src[t], s2 = csr_src[t + 2];
            int s3 = csr_src[t + 4], s4 = csr_src[t + 6];
            uint4 r1 = *(const uint4*)(h1 + (size_t)s1 * 256 + hl * 8);
            uint4 r2 = *(const uint4*)(h1 + (size_t)s2 * 256 + hl * 8);
            uint4 r3 = *(const uint4*)(h1 + (size_t)s3 * 256 + hl * 8);
            uint4 r4 = *(const uint4*)(h1 + (size_t)s4 * 256 + hl * 8);
            float w1 = eexp(lrelu(a_s[s1 * 4 + h] + ad));
            float w2 = eexp(lrelu(a_s[s2 * 4 + h] + ad));
            float w3 = eexp(lrelu(a_s[s3 * 4 + h] + ad));
            float w4 = eexp(lrelu(a_s[s4 * 4 + h] + ad));
            l += (w1 + w2) + (w3 + w4);
            acc[0] += (w1 * bfLo(r1.x) + w2 * bfLo(r2.x)) + (w3 * bfLo(r3.x) + w4 * bfLo(r4.x));
            acc[1] += (w1 * bfHi(r1.x) + w2 * bfHi(r2.x)) + (w3 * bfHi(r3.x) + w4 * bfHi(r4.x));
            acc[2] += (w1 * bfLo(r1.y) + w2 * bfLo(r2.y)) + (w3 * bfLo(r3.y) + w4 * bfLo(r4.y));
            acc[3] += (w1 * bfHi(r1.y) + w2 * bfHi(r2.y)) + (w3 * bfHi(r3.y) + w4 * bfHi(r4.y));
            acc[4] += (w1 * bfLo(r1.z) + w2 * bfLo(r2.z)) + (w3 * bfLo(r3.z) + w4 * bfLo(r4.z));
            acc[5] += (w1 * bfHi(r1.z) + w2 * bfHi(r2.z)) + (w3 * bfHi(r3.z) + w4 * bfHi(r4.z));
            acc[6] += (w1 * bfLo(r1.w) + w2 * bfLo(r2.w)) + (w3 * bfLo(r3.w) + w4 * bfLo(r4.w));
            acc[7] += (w1 * bfHi(r1.w) + w2 * bfHi(r2.w)) + (w3 * bfHi(r3.w) + w4 * bfHi(r4.w));
        }
        for (; t < hi; t += 2) {
            int s1 = csr_src[t];
            uint4 r1 = *(const uint4*)(h1 + (size_t)s1 * 256 + hl * 8);
            float w1 = eexp(lrelu(a_s[s1 * 4 + h] + ad));
            l += w1;
            acc[0] += w1 * bfLo(r1.x);
            acc[1] += w1 * bfHi(r1.x);
            acc[2] += w1 * bfLo(r1.y);
            acc[3] += w1 * bfHi(r1.y);
            acc[4] += w1 * bfLo(r1.z);
            acc[5] += w1 * bfHi(r1.z);
            acc[6] += w1 * bfLo(r1.w);
            acc[7] += w1 * bfHi(r1.w);
        }
        l += __shfl_xor(l, 32, 64);
#pragma unroll
        for (int j = 0; j < 8; ++j) acc[j] += __shfl_xor(acc[j], 32, 64);
        if (half == 0) {
            float inv = 1.f / (l + 1e-16f);
            BF8 o;
#pragma unroll
            for (int j = 0; j < 8; ++j) {
                float val = acc[j] * inv + b1v[j];
                val = val > 0.f ? val : (__expf(val) - 1.f);
                o.e[j] = __float2bfloat16(val);
            }
            *(bf16x8*)(&strip[w][i][hl * 8]) = o.v;
        }
    }

    // ---- per-wave MFMA epilogue (no barrier) ----
    // A (first operand, D-rows = 16 output channels per cb): W2t from global.
    // B (second operand, D-cols = nodes, 0-3 valid): wave's LDS strip.
    const int q = lane >> 4;
    const int cl = lane & 15;
    const int jj = cl & 3;  // node column, 4x duplicated (broadcast reads)
    f32x4 d2[4];
#pragma unroll
    for (int cb = 0; cb < 4; ++cb) d2[cb] = (f32x4){0.f, 0.f, 0.f, 0.f};
#pragma unroll
    for (int kc = 0; kc < 8; ++kc) {
        bf16x8 bAct = *(const bf16x8*)(&strip[w][jj][kc * 32 + q * 8]);
#pragma unroll
        for (int cb = 0; cb < 4; ++cb) {
            bf16x8 aW = *(const bf16x8*)(W2t + (size_t)(cb * 16 + cl) * 256 + kc * 32 + q * 8);
            d2[cb] = __builtin_amdgcn_mfma_f32_16x16x32_bf16(aW, bAct, d2[cb], 0, 0, 0);
        }
    }
    const int node = wn0 + cl;             // valid when cl < 4
    const bool act_lane = (cl < 4) && (node < N);
    float pas = 0.f, pad = 0.f;
#pragma unroll
    for (int cb = 0; cb < 4; ++cb) {
        if (act_lane) {
            BF4 o;
#pragma unroll
            for (int r = 0; r < 4; ++r) o.e[r] = __float2bfloat16(d2[cb][r]);
            *(uint2*)(h2b + (size_t)node * 64 + cb * 16 + q * 4) = o.u;
        }
#pragma unroll
        for (int r = 0; r < 4; ++r) {
            int c = cb * 16 + q * 4 + r;
            pas += d2[cb][r] * loadF(att_src2, c, f32);
            pad += d2[cb][r] * loadF(att_dst2, c, f32);
        }
    }
    pas += __shfl_xor(pas, 16, 64);
    pas += __shfl_xor(pas, 32, 64);
    pad += __shfl_xor(pad, 16, 64);
    pad += __shfl_xor(pad, 32, 64);
    if (lane < 4 && wn0 + lane < N) {
        a_s2[wn0 + lane] = pas;
        a_d2[wn0 + lane] = pad;
    }
}

// ---------------- fused layer-2: 4 edges per wave, x4-deep gathers ----------
// quarter q = lane>>4 owns one edge; 16 lanes x uint2 (4 bf16) cover the
// 64-ch row. 4 independent gathers in flight per quarter (stride 16).
__global__ void fused2_kernel(const int* __restrict__ row_start,
                              const int* __restrict__ csr_src,
                              const float* __restrict__ a_s,
                              const float* __restrict__ a_d,
                              const __hip_bfloat16* __restrict__ h2b,
                              const void* __restrict__ bias2,
                              const int* __restrict__ flags,
                              float* __restrict__ out, int N) {
    const bool f32 = (flags[0] != 0);
    int n = blockIdx.x * 4 + (threadIdx.x >> 6);
    if (n >= N) return;
    int lane = threadIdx.x & 63;
    int q = lane >> 4;          // which edge of 4
    int hl = lane & 15;         // channels hl*4 .. hl*4+3
    int lo = row_start[n], hi = row_start[n + 1];
    float ad = a_d[n];
    float l = 0.f, a0 = 0.f, a1 = 0.f, a2 = 0.f, a3 = 0.f;
    int t = lo + q;
    for (; t + 12 < hi; t += 16) {             // 4 edges per quarter per iter
        int s1 = csr_src[t],     s2 = csr_src[t + 4];
        int s3 = csr_src[t + 8], s4 = csr_src[t + 12];
        uint2 r1 = *(const uint2*)(h2b + (size_t)s1 * 64 + hl * 4);
        uint2 r2 = *(const uint2*)(h2b + (size_t)s2 * 64 + hl * 4);
        uint2 r3 = *(const uint2*)(h2b + (size_t)s3 * 64 + hl * 4);
        uint2 r4 = *(const uint2*)(h2b + (size_t)s4 * 64 + hl * 4);
        float w1 = eexp(lrelu(a_s[s1] + ad));
        float w2 = eexp(lrelu(a_s[s2] + ad));
        float w3 = eexp(lrelu(a_s[s3] + ad));
        float w4 = eexp(lrelu(a_s[s4] + ad));
        l += (w1 + w2) + (w3 + w4);
        a0 += (w1 * bfLo(r1.x) + w2 * bfLo(r2.x)) + (w3 * bfLo(r3.x) + w4 * bfLo(r4.x));
        a1 += (w1 * bfHi(r1.x) + w2 * bfHi(r2.x)) + (w3 * bfHi(r3.x) + w4 * bfHi(r4.x));
        a2 += (w1 * bfLo(r1.y) + w2 * bfLo(r2.y)) + (w3 * bfLo(r3.y) + w4 * bfLo(r4.y));
        a3 += (w1 * bfHi(r1.y) + w2 * bfHi(r2.y)) + (w3 * bfHi(r3.y) + w4 * bfHi(r4.y));
    }
    for (; t < hi; t += 4) {
        int s1 = csr_src[t];
        uint2 r1 = *(const uint2*)(h2b + (size_t)s1 * 64 + hl * 4);
        float w1 = eexp(lrelu(a_s[s1] + ad));
        l += w1;
        a0 += w1 * bfLo(r1.x);
        a1 += w1 * bfHi(r1.x);
        a2 += w1 * bfLo(r1.y);
        a3 += w1 * bfHi(r1.y);
    }
#pragma unroll
    for (int m = 16; m <= 32; m <<= 1) {
        l  += __shfl_xor(l, m, 64);
        a0 += __shfl_xor(a0, m, 64);
        a1 += __shfl_xor(a1, m, 64);
        a2 += __shfl_xor(a2, m, 64);
        a3 += __shfl_xor(a3, m, 64);
    }
    if (q == 0) {
        float inv = 1.f / (l + 1e-16f);
        float4 o;
        o.x = a0 * inv + loadF(bias2, hl * 4 + 0, f32);
        o.y = a1 * inv + loadF(bias2, hl * 4 + 1, f32);
        o.z = a2 * inv + loadF(bias2, hl * 4 + 2, f32);
        o.w = a3 * inv + loadF(bias2, hl * 4 + 3, f32);
        *(float4*)(out + (size_t)n * 64 + hl * 4) = o;
    }
}

__global__ void sentinel_kernel(float* __restrict__ out, int n, float C) {
    int i = blockIdx.x * blockDim.x + threadIdx.x;
    if (i < n) out[i] = C;
}

static inline size_t al256(size_t x) { return (x + 255) & ~(size_t)255; }

extern "C" void kernel_launch(void* const* d_in, const int* in_sizes, int n_in,
                              void* d_out, int out_size, void* d_ws, size_t ws_size,
                              hipStream_t stream) {
    const void* x     = d_in[0];
    const int*  ei    = (const int*)d_in[1];
    const void* W1    = d_in[2];
    const void* as1w  = d_in[3];
    const void* ad1w  = d_in[4];
    const void* bias1 = d_in[5];
    const void* W2    = d_in[6];
    const void* as2w  = d_in[7];
    const void* ad2w  = d_in[8];
    const void* bias2 = d_in[9];

    const int N  = in_sizes[0] / 128;  // 50000
    const int E  = in_sizes[1] / 2;    // 800000
    const int Et = E + N;
    const int NCH = (N + 255) / 256;

    char* p = (char*)d_ws;
    int* flags = (int*)p;                       p += 256;
    int* counts = (int*)p;                      p += al256((size_t)N * 4);
    int* row_start = (int*)p;                   p += al256(((size_t)N + 1) * 4);
    int* rank = (int*)p;                        p += al256((size_t)Et * 4);
    int* blocksum = (int*)p;                    p += al256((size_t)NCH * 4);
    int* blockoff = (int*)p;                    p += al256((size_t)NCH * 4);
    int* csr_src = (int*)p;                     p += al256((size_t)Et * 4);
    float* a_s1 = (float*)p;                    p += al256((size_t)N * 4 * 4);
    float* a_d1 = (float*)p;                    p += al256((size_t)N * 4 * 4);
    __hip_bfloat16* W1t = (__hip_bfloat16*)p;   p += al256(256 * 128 * 2);
    __hip_bfloat16* W2t = (__hip_bfloat16*)p;   p += al256(64 * 256 * 2);
    __hip_bfloat16* h1 = (__hip_bfloat16*)p;    p += al256((size_t)N * 256 * 2);
    __hip_bfloat16* h2b = (__hip_bfloat16*)p;   p += al256((size_t)N * 64 * 2);
    float* a_s2 = (float*)p;                    p += al256((size_t)N * 4);
    float* a_d2 = (float*)p;                    p += al256((size_t)N * 4);

    const size_t need = (size_t)(p - (char*)d_ws);
    if (ws_size < need) {
        sentinel_kernel<<<(out_size + 255) / 256, 256, 0, stream>>>(
            (float*)d_out, out_size, 5.0f);
        return;
    }

    const int PB = (256 * 128 + 64 * 256) / 256;  // 192 prep blocks
    const int CB = (Et + 1023) / 1024;            // count blocks (4 edges/thread)
    const int SB = (Et + 1023) / 1024;            // scatter blocks
    const int G1 = (N + 15) / 16;                 // gemm1 blocks

    // detect flags + zero counts in one dispatch (no memsets)
    detect_kernel<<<2 + NCH, 256, 0, stream>>>(x, ei, flags, counts, N);
    // prep (weight transpose) || count+rank (single atomic pass)
    prep_count_kernel<<<PB + CB, 256, 0, stream>>>(W1, W2, ei, flags, W1t, W2t,
                                                   counts, rank, E, N, PB);
    scanA_kernel<<<NCH, 256, 0, stream>>>(counts, blocksum, N);
    scanB_kernel<<<1, 1024, 0, stream>>>(blocksum, blockoff, NCH);
    scanC_kernel<<<NCH, 256, 0, stream>>>(counts, blockoff, row_start, N, Et);
    // scatter (no atomics: row_start[d] + rank[e]) || gemm1
    scatter_gemm1_kernel<<<SB + G1, 256, 0, stream>>>(ei, E, N, flags, rank,
                                                      row_start, csr_src, x, W1t,
                                                      as1w, ad1w, h1, a_s1, a_d1, SB);
    // fused aggregation + per-wave layer-2 GEMM (no barrier, no h1act round-trip)
    fused1_gemm2_kernel<<<(N + F1_NODES - 1) / F1_NODES, 256, 0, stream>>>(
        row_start, csr_src, a_s1, a_d1, h1, bias1, W2t, as2w, ad2w, flags,
        h2b, a_s2, a_d2, N);
    fused2_kernel<<<(N + 3) / 4, 256, 0, stream>>>(row_start, csr_src, a_s2, a_d2,
                                                   h2b, bias2, flags, (float*)d_out, N);
}

// Round 6
// 293.622 us; speedup vs baseline: 1.0991x; 1.0991x over previous
//
#include <hip/hip_runtime.h>
#include <hip/hip_bf16.h>

#define NEG_SLOPE 0.2f
#define F1_NODES 16
#define F1_PAD 264  // 256 + 8 bf16: row stride 528B -> rotating bank groups

typedef short bf16x8 __attribute__((ext_vector_type(8)));
typedef float f32x4 __attribute__((ext_vector_type(4)));

union BF8 { bf16x8 v; __hip_bfloat16 e[8]; };

__device__ __forceinline__ float b2f(__hip_bfloat16 b) { return __bfloat162float(b); }

__device__ __forceinline__ float loadF(const void* p, int i, bool f32) {
    return f32 ? ((const float*)p)[i] : b2f(((const __hip_bfloat16*)p)[i]);
}

__device__ __forceinline__ void getSD(const int* ei, int e, int E, bool i64, int N,
                                      int& s, int& d) {
    if (e < E) {
        if (i64) { s = ei[2 * e]; d = ei[2 * (E + e)]; }
        else     { s = ei[e];     d = ei[E + e]; }
    } else { s = e - E; d = s; }
    s = min(max(s, 0), N - 1);
    d = min(max(d, 0), N - 1);
}

// lrelu(v) = max(v, 0.2v) for slope in (0,1): 2 VALU ops, no cndmask
__device__ __forceinline__ float lrelu(float v) { return fmaxf(v, NEG_SLOPE * v); }
// exp without max-subtraction: logits ~N(0,1.5); clamp for overflow safety.
__device__ __forceinline__ float eexp(float v) { return __expf(fminf(v, 80.f)); }

__device__ __forceinline__ float bfLo(unsigned u) { return __uint_as_float(u << 16); }
__device__ __forceinline__ float bfHi(unsigned u) { return __uint_as_float(u & 0xffff0000u); }

// block 0 -> flags[0] (floats f32?); block 1 -> flags[1] (edges int64?);
// blocks 2.. zero the counts array. Deterministic writes, no pre-memset needed.
__global__ void detect_kernel(const void* x, const int* ei, int* flags,
                              int* counts, int N) {
    if (blockIdx.x == 0) {
        int bad = 0;
        for (int i = threadIdx.x; i < 8192; i += 256) {
            unsigned short u = ((const unsigned short*)x)[i];
            if (((u >> 7) & 0xFF) >= 140) bad = 1;
        }
        __shared__ int r[4];
        unsigned long long m = __ballot(bad);
        if ((threadIdx.x & 63) == 0) r[threadIdx.x >> 6] = (m != 0ull);
        __syncthreads();
        if (threadIdx.x == 0) flags[0] = (r[0] | r[1] | r[2] | r[3]) ? 1 : 0;
    } else if (blockIdx.x == 1) {
        __shared__ int cnt;
        if (threadIdx.x == 0) cnt = 0;
        __syncthreads();
        int z = 0;
        for (int i = threadIdx.x; i < 4096; i += 256)
            if (ei[2 * i + 1] == 0) ++z;
        atomicAdd(&cnt, z);
        __syncthreads();
        if (threadIdx.x == 0) flags[1] = (cnt >= 2048) ? 1 : 0;
    } else {
        int i = (blockIdx.x - 2) * 256 + threadIdx.x;
        if (i < N) counts[i] = 0;
    }
}

// merged: blocks [0,PB) transpose weights; blocks [PB,..) count in-degrees AND
// capture each edge's rank within its dst segment (atomicAdd return value).
// 8 edges per thread = 8 independent atomic round-trips in flight (R6: the
// count pass is the biggest non-top5 kernel; if latency-bound this halves it).
__global__ void prep_count_kernel(const void* __restrict__ W1,
                                  const void* __restrict__ W2,
                                  const int* __restrict__ ei,
                                  const int* __restrict__ flags,
                                  __hip_bfloat16* __restrict__ W1t,
                                  __hip_bfloat16* __restrict__ W2t,
                                  int* __restrict__ counts,
                                  int* __restrict__ rank,
                                  int E, int N, int PB) {
    if ((int)blockIdx.x < PB) {
        const bool f32 = (flags[0] != 0);
        int i = blockIdx.x * 256 + threadIdx.x;
        if (i < 256 * 128) {
            int c = i >> 7, k = i & 127;
            W1t[c * 128 + k] = __float2bfloat16(loadF(W1, k * 256 + c, f32));
        } else if (i < 256 * 128 + 64 * 256) {
            int t = i - 256 * 128, c = t >> 8, k = t & 255;
            W2t[c * 256 + k] = __float2bfloat16(loadF(W2, k * 64 + c, f32));
        }
    } else {
        const bool i64 = (flags[1] != 0);
        const int Et = E + N;
        int base = (blockIdx.x - PB) * 2048 + threadIdx.x;
#pragma unroll
        for (int j = 0; j < 8; ++j) {
            int e = base + j * 256;
            if (e < Et) {
                int s, d;
                getSD(ei, e, E, i64, N, s, d);
                rank[e] = atomicAdd(&counts[d], 1);
            }
        }
    }
}

// ---------------- CSR build ----------------

__global__ void scanA_kernel(const int* __restrict__ counts,
                             int* __restrict__ blocksum, int N) {
    int b = blockIdx.x;
    int i = b * 256 + threadIdx.x;
    int v = (i < N) ? counts[i] : 0;
    for (int off = 32; off >= 1; off >>= 1) v += __shfl_down(v, off, 64);
    __shared__ int ws[4];
    if ((threadIdx.x & 63) == 0) ws[threadIdx.x >> 6] = v;
    __syncthreads();
    if (threadIdx.x == 0) blocksum[b] = ws[0] + ws[1] + ws[2] + ws[3];
}

// scanC with scanB folded in: each block reduces blocksum[0..b) itself
// (nb <= 256, one element per thread) -> one dispatch fewer, no blockoff buf.
__global__ void scanC_kernel(const int* __restrict__ counts,
                             const int* __restrict__ blocksum,
                             int* __restrict__ row_start, int N, int Et, int nb) {
    int b = blockIdx.x;
    int t = threadIdx.x;
    __shared__ int ws[4];
    __shared__ int boff_s;
    // --- block offset: sum of blocksum[0..b) ---
    {
        int v = (t < nb && t < b) ? blocksum[t] : 0;
        for (int off = 32; off >= 1; off >>= 1) v += __shfl_down(v, off, 64);
        if ((t & 63) == 0) ws[t >> 6] = v;
        __syncthreads();
        if (t == 0) boff_s = ws[0] + ws[1] + ws[2] + ws[3];
        __syncthreads();
    }
    const int boff = boff_s;
    __syncthreads();  // ws reused below
    int i = b * 256 + t;
    int own = (i < N) ? counts[i] : 0;
    int v = own;
    int lane = t & 63, w = t >> 6;
    for (int d = 1; d < 64; d <<= 1) {
        int u = __shfl_up(v, d, 64);
        if (lane >= d) v += u;
    }
    if (lane == 63) ws[w] = v;
    __syncthreads();
    int woff = 0;
#pragma unroll
    for (int q = 0; q < 4; ++q) woff += (q < w) ? ws[q] : 0;
    int exc = boff + woff + v - own;
    if (i < N) row_start[i] = exc;
    if (i == N - 1) row_start[N] = Et;
}

// ---------------- scatter (CSR fill, NO atomics) merged with layer-1 GEMM ----
// position = row_start[d] + rank[e]. 8 edges/thread for MLP.
__global__ void scatter_gemm1_kernel(const int* __restrict__ ei, int E, int N,
                                     const int* __restrict__ flags,
                                     const int* __restrict__ rank,
                                     const int* __restrict__ row_start,
                                     int* __restrict__ csr_src,
                                     const void* __restrict__ x,
                                     const __hip_bfloat16* __restrict__ W1t,
                                     const void* __restrict__ att_src,
                                     const void* __restrict__ att_dst,
                                     __hip_bfloat16* __restrict__ h1,
                                     float* __restrict__ a_s,
                                     float* __restrict__ a_d, int SB) {
    if ((int)blockIdx.x < SB) {
        const bool i64 = (flags[1] != 0);
        const int Et = E + N;
        int base = blockIdx.x * 2048 + threadIdx.x;
#pragma unroll
        for (int j = 0; j < 8; ++j) {
            int e = base + j * 256;
            if (e < Et) {
                int s, d;
                getSD(ei, e, E, i64, N, s, d);
                csr_src[row_start[d] + rank[e]] = s;
            }
        }
        return;
    }
    const bool f32 = (flags[0] != 0);
    const int n0 = (blockIdx.x - SB) * 16;
    const int w = threadIdx.x >> 6;
    const int lane = threadIdx.x & 63;
    const int q = lane >> 4;
    const int cl = lane & 15;

    bf16x8 a[4];
    const int an = min(n0 + cl, N - 1);
    if (f32) {
        const float* xp = (const float*)x + (size_t)an * 128;
#pragma unroll
        for (int kc = 0; kc < 4; ++kc) {
            f32x4 v0 = *(const f32x4*)(xp + kc * 32 + q * 8);
            f32x4 v1 = *(const f32x4*)(xp + kc * 32 + q * 8 + 4);
            BF8 t;
#pragma unroll
            for (int i = 0; i < 4; ++i) {
                t.e[i]     = __float2bfloat16(v0[i]);
                t.e[i + 4] = __float2bfloat16(v1[i]);
            }
            a[kc] = t.v;
        }
    } else {
        const __hip_bfloat16* xp = (const __hip_bfloat16*)x + (size_t)an * 128;
#pragma unroll
        for (int kc = 0; kc < 4; ++kc)
            a[kc] = *(const bf16x8*)(xp + kc * 32 + q * 8);
    }
    f32x4 acc[4];
#pragma unroll
    for (int ct = 0; ct < 4; ++ct) acc[ct] = (f32x4){0.f, 0.f, 0.f, 0.f};
#pragma unroll
    for (int kc = 0; kc < 4; ++kc) {
#pragma unroll
        for (int ct = 0; ct < 4; ++ct) {
            int col = w * 64 + ct * 16 + cl;
            bf16x8 b = *(const bf16x8*)(W1t + (size_t)col * 128 + kc * 32 + q * 8);
            acc[ct] = __builtin_amdgcn_mfma_f32_16x16x32_bf16(a[kc], b, acc[ct], 0, 0, 0);
        }
    }
    float asw[4], adw[4];
#pragma unroll
    for (int ct = 0; ct < 4; ++ct) {
        int col = w * 64 + ct * 16 + cl;
        asw[ct] = loadF(att_src, col, f32);
        adw[ct] = loadF(att_dst, col, f32);
    }
#pragma unroll
    for (int r = 0; r < 4; ++r) {
        int n = n0 + q * 4 + r;
        if (n < N) {
#pragma unroll
            for (int ct = 0; ct < 4; ++ct)
                h1[(size_t)n * 256 + w * 64 + ct * 16 + cl] = __float2bfloat16(acc[ct][r]);
        }
        float pas = acc[0][r] * asw[0] + acc[1][r] * asw[1]
                  + acc[2][r] * asw[2] + acc[3][r] * asw[3];
        float pad = acc[0][r] * adw[0] + acc[1][r] * adw[1]
                  + acc[2][r] * adw[2] + acc[3][r] * adw[3];
#pragma unroll
        for (int m = 1; m <= 8; m <<= 1) {
            pas += __shfl_xor(pas, m, 64);
            pad += __shfl_xor(pad, m, 64);
        }
        if (cl == 0 && n < N) {
            a_s[n * 4 + w] = pas;
            a_d[n * 4 + w] = pad;
        }
    }
}

// ---------------- fused layer-1 aggregation + layer-2 GEMM (R4 version) -----
// R5 lesson: per-wave barrier-free epilogue regressed (4x MFMA work, 4x W2t
// re-stream, 32 scalar att2 loads) — the shared 4-wave epilogue is cheaper
// than the barrier it needs. This is the best measured config (89.5us).
__global__ void fused1_gemm2_kernel(const int* __restrict__ row_start,
                                    const int* __restrict__ csr_src,
                                    const float* __restrict__ a_s,
                                    const float* __restrict__ a_d,
                                    const __hip_bfloat16* __restrict__ h1,
                                    const void* __restrict__ bias1,
                                    const __hip_bfloat16* __restrict__ W2t,
                                    const void* __restrict__ att_src2,
                                    const void* __restrict__ att_dst2,
                                    const int* __restrict__ flags,
                                    __hip_bfloat16* __restrict__ h2b,
                                    float* __restrict__ a_s2,
                                    float* __restrict__ a_d2, int N) {
    const bool f32 = (flags[0] != 0);
    __shared__ __hip_bfloat16 tile[F1_NODES][F1_PAD];
    __shared__ float a2p[F1_NODES][4][2];
    const int w = threadIdx.x >> 6;
    const int lane = threadIdx.x & 63;
    const int half = lane >> 5;   // which edge of the pair
    const int hl = lane & 31;     // channels hl*8 .. hl*8+7
    const int h = hl >> 3;        // head of this channel group
    const int n0 = blockIdx.x * F1_NODES;

    // bias for this lane's 8 channels (same for all nodes) — hoisted
    float b1v[8];
#pragma unroll
    for (int i = 0; i < 8; ++i) b1v[i] = loadF(bias1, hl * 8 + i, f32);

    for (int i = 0; i < 4; ++i) {
        const int n = n0 + w * 4 + i;
        const int row = w * 4 + i;
        if (n < N) {
            int lo = row_start[n], hi = row_start[n + 1];
            float ad = a_d[n * 4 + h];
            float l = 0.f;
            float acc[8] = {0.f, 0.f, 0.f, 0.f, 0.f, 0.f, 0.f, 0.f};
            int t = lo + half;
            for (; t + 6 < hi; t += 8) {               // 4 edges per half per iter
                int s1 = csr_src[t], s2 = csr_src[t + 2];
                int s3 = csr_src[t + 4], s4 = csr_src[t + 6];
                uint4 r1 = *(const uint4*)(h1 + (size_t)s1 * 256 + hl * 8);
                uint4 r2 = *(const uint4*)(h1 + (size_t)s2 * 256 + hl * 8);
                uint4 r3 = *(const uint4*)(h1 + (size_t)s3 * 256 + hl * 8);
                uint4 r4 = *(const uint4*)(h1 + (size_t)s4 * 256 + hl * 8);
                float w1 = eexp(lrelu(a_s[s1 * 4 + h] + ad));
                float w2 = eexp(lrelu(a_s[s2 * 4 + h] + ad));
                float w3 = eexp(lrelu(a_s[s3 * 4 + h] + ad));
                float w4 = eexp(lrelu(a_s[s4 * 4 + h] + ad));
                l += (w1 + w2) + (w3 + w4);
                acc[0] += (w1 * bfLo(r1.x) + w2 * bfLo(r2.x)) + (w3 * bfLo(r3.x) + w4 * bfLo(r4.x));
                acc[1] += (w1 * bfHi(r1.x) + w2 * bfHi(r2.x)) + (w3 * bfHi(r3.x) + w4 * bfHi(r4.x));
                acc[2] += (w1 * bfLo(r1.y) + w2 * bfLo(r2.y)) + (w3 * bfLo(r3.y) + w4 * bfLo(r4.y));
                acc[3] += (w1 * bfHi(r1.y) + w2 * bfHi(r2.y)) + (w3 * bfHi(r3.y) + w4 * bfHi(r4.y));
                acc[4] += (w1 * bfLo(r1.z) + w2 * bfLo(r2.z)) + (w3 * bfLo(r3.z) + w4 * bfLo(r4.z));
                acc[5] += (w1 * bfHi(r1.z) + w2 * bfHi(r2.z)) + (w3 * bfHi(r3.z) + w4 * bfHi(r4.z));
                acc[6] += (w1 * bfLo(r1.w) + w2 * bfLo(r2.w)) + (w3 * bfLo(r3.w) + w4 * bfLo(r4.w));
                acc[7] += (w1 * bfHi(r1.w) + w2 * bfHi(r2.w)) + (w3 * bfHi(r3.w) + w4 * bfHi(r4.w));
            }
            for (; t < hi; t += 2) {
                int s1 = csr_src[t];
                uint4 r1 = *(const uint4*)(h1 + (size_t)s1 * 256 + hl * 8);
                float w1 = eexp(lrelu(a_s[s1 * 4 + h] + ad));
                l += w1;
                acc[0] += w1 * bfLo(r1.x);
                acc[1] += w1 * bfHi(r1.x);
                acc[2] += w1 * bfLo(r1.y);
                acc[3] += w1 * bfHi(r1.y);
                acc[4] += w1 * bfLo(r1.z);
                acc[5] += w1 * bfHi(r1.z);
                acc[6] += w1 * bfLo(r1.w);
                acc[7] += w1 * bfHi(r1.w);
            }
            l += __shfl_xor(l, 32, 64);
#pragma unroll
            for (int j = 0; j < 8; ++j) acc[j] += __shfl_xor(acc[j], 32, 64);
            if (half == 0) {
                float inv = 1.f / (l + 1e-16f);
                BF8 o;
#pragma unroll
                for (int j = 0; j < 8; ++j) {
                    float val = acc[j] * inv + b1v[j];
                    val = val > 0.f ? val : (__expf(val) - 1.f);
                    o.e[j] = __float2bfloat16(val);
                }
                *(bf16x8*)(&tile[row][hl * 8]) = o.v;
            }
        } else if (half == 0) {
            // zero missing rows so the MFMA epilogue reads clean data
            BF8 z;
#pragma unroll
            for (int j = 0; j < 8; ++j) z.e[j] = __float2bfloat16(0.f);
            *(bf16x8*)(&tile[row][hl * 8]) = z.v;
        }
    }
    __syncthreads();

    // ---- MFMA epilogue: [16 nodes] x [64 ch] = A(16x256, LDS) * W2t ----
    const int q = lane >> 4;
    const int cl = lane & 15;
    f32x4 acc2 = (f32x4){0.f, 0.f, 0.f, 0.f};
#pragma unroll
    for (int kc = 0; kc < 8; ++kc) {
        bf16x8 a = *(const bf16x8*)(&tile[cl][kc * 32 + q * 8]);
        bf16x8 b = *(const bf16x8*)(W2t + (size_t)(w * 16 + cl) * 256 + kc * 32 + q * 8);
        acc2 = __builtin_amdgcn_mfma_f32_16x16x32_bf16(a, b, acc2, 0, 0, 0);
    }
    float asw = loadF(att_src2, w * 16 + cl, f32);
    float adw = loadF(att_dst2, w * 16 + cl, f32);
#pragma unroll
    for (int r = 0; r < 4; ++r) {
        int n = n0 + q * 4 + r;
        if (n < N) h2b[(size_t)n * 64 + w * 16 + cl] = __float2bfloat16(acc2[r]);
        float pas = acc2[r] * asw;
        float pad = acc2[r] * adw;
#pragma unroll
        for (int m = 1; m <= 8; m <<= 1) {
            pas += __shfl_xor(pas, m, 64);
            pad += __shfl_xor(pad, m, 64);
        }
        if (cl == 0) {
            a2p[q * 4 + r][w][0] = pas;
            a2p[q * 4 + r][w][1] = pad;
        }
    }
    __syncthreads();
    int t = threadIdx.x;
    if (t < F1_NODES) {
        int n = n0 + t;
        if (n < N) {
            a_s2[n] = (a2p[t][0][0] + a2p[t][1][0]) + (a2p[t][2][0] + a2p[t][3][0]);
            a_d2[n] = (a2p[t][0][1] + a2p[t][1][1]) + (a2p[t][2][1] + a2p[t][3][1]);
        }
    }
}

// ---------------- fused layer-2: 4 edges per wave, x4-deep gathers ----------
// quarter q = lane>>4 owns one edge; 16 lanes x uint2 (4 bf16) cover the
// 64-ch row. 4 independent gathers in flight per quarter (stride 16).
__global__ void fused2_kernel(const int* __restrict__ row_start,
                              const int* __restrict__ csr_src,
                              const float* __restrict__ a_s,
                              const float* __restrict__ a_d,
                              const __hip_bfloat16* __restrict__ h2b,
                              const void* __restrict__ bias2,
                              const int* __restrict__ flags,
                              float* __restrict__ out, int N) {
    const bool f32 = (flags[0] != 0);
    int n = blockIdx.x * 4 + (threadIdx.x >> 6);
    if (n >= N) return;
    int lane = threadIdx.x & 63;
    int q = lane >> 4;          // which edge of 4
    int hl = lane & 15;         // channels hl*4 .. hl*4+3
    int lo = row_start[n], hi = row_start[n + 1];
    float ad = a_d[n];
    float l = 0.f, a0 = 0.f, a1 = 0.f, a2 = 0.f, a3 = 0.f;
    int t = lo + q;
    for (; t + 12 < hi; t += 16) {             // 4 edges per quarter per iter
        int s1 = csr_src[t],     s2 = csr_src[t + 4];
        int s3 = csr_src[t + 8], s4 = csr_src[t + 12];
        uint2 r1 = *(const uint2*)(h2b + (size_t)s1 * 64 + hl * 4);
        uint2 r2 = *(const uint2*)(h2b + (size_t)s2 * 64 + hl * 4);
        uint2 r3 = *(const uint2*)(h2b + (size_t)s3 * 64 + hl * 4);
        uint2 r4 = *(const uint2*)(h2b + (size_t)s4 * 64 + hl * 4);
        float w1 = eexp(lrelu(a_s[s1] + ad));
        float w2 = eexp(lrelu(a_s[s2] + ad));
        float w3 = eexp(lrelu(a_s[s3] + ad));
        float w4 = eexp(lrelu(a_s[s4] + ad));
        l += (w1 + w2) + (w3 + w4);
        a0 += (w1 * bfLo(r1.x) + w2 * bfLo(r2.x)) + (w3 * bfLo(r3.x) + w4 * bfLo(r4.x));
        a1 += (w1 * bfHi(r1.x) + w2 * bfHi(r2.x)) + (w3 * bfHi(r3.x) + w4 * bfHi(r4.x));
        a2 += (w1 * bfLo(r1.y) + w2 * bfLo(r2.y)) + (w3 * bfLo(r3.y) + w4 * bfLo(r4.y));
        a3 += (w1 * bfHi(r1.y) + w2 * bfHi(r2.y)) + (w3 * bfHi(r3.y) + w4 * bfHi(r4.y));
    }
    for (; t < hi; t += 4) {
        int s1 = csr_src[t];
        uint2 r1 = *(const uint2*)(h2b + (size_t)s1 * 64 + hl * 4);
        float w1 = eexp(lrelu(a_s[s1] + ad));
        l += w1;
        a0 += w1 * bfLo(r1.x);
        a1 += w1 * bfHi(r1.x);
        a2 += w1 * bfLo(r1.y);
        a3 += w1 * bfHi(r1.y);
    }
#pragma unroll
    for (int m = 16; m <= 32; m <<= 1) {
        l  += __shfl_xor(l, m, 64);
        a0 += __shfl_xor(a0, m, 64);
        a1 += __shfl_xor(a1, m, 64);
        a2 += __shfl_xor(a2, m, 64);
        a3 += __shfl_xor(a3, m, 64);
    }
    if (q == 0) {
        float inv = 1.f / (l + 1e-16f);
        float4 o;
        o.x = a0 * inv + loadF(bias2, hl * 4 + 0, f32);
        o.y = a1 * inv + loadF(bias2, hl * 4 + 1, f32);
        o.z = a2 * inv + loadF(bias2, hl * 4 + 2, f32);
        o.w = a3 * inv + loadF(bias2, hl * 4 + 3, f32);
        *(float4*)(out + (size_t)n * 64 + hl * 4) = o;
    }
}

__global__ void sentinel_kernel(float* __restrict__ out, int n, float C) {
    int i = blockIdx.x * blockDim.x + threadIdx.x;
    if (i < n) out[i] = C;
}

static inline size_t al256(size_t x) { return (x + 255) & ~(size_t)255; }

extern "C" void kernel_launch(void* const* d_in, const int* in_sizes, int n_in,
                              void* d_out, int out_size, void* d_ws, size_t ws_size,
                              hipStream_t stream) {
    const void* x     = d_in[0];
    const int*  ei    = (const int*)d_in[1];
    const void* W1    = d_in[2];
    const void* as1w  = d_in[3];
    const void* ad1w  = d_in[4];
    const void* bias1 = d_in[5];
    const void* W2    = d_in[6];
    const void* as2w  = d_in[7];
    const void* ad2w  = d_in[8];
    const void* bias2 = d_in[9];

    const int N  = in_sizes[0] / 128;  // 50000
    const int E  = in_sizes[1] / 2;    // 800000
    const int Et = E + N;
    const int NCH = (N + 255) / 256;

    char* p = (char*)d_ws;
    int* flags = (int*)p;                       p += 256;
    int* counts = (int*)p;                      p += al256((size_t)N * 4);
    int* row_start = (int*)p;                   p += al256(((size_t)N + 1) * 4);
    int* rank = (int*)p;                        p += al256((size_t)Et * 4);
    int* blocksum = (int*)p;                    p += al256((size_t)NCH * 4);
    int* csr_src = (int*)p;                     p += al256((size_t)Et * 4);
    float* a_s1 = (float*)p;                    p += al256((size_t)N * 4 * 4);
    float* a_d1 = (float*)p;                    p += al256((size_t)N * 4 * 4);
    __hip_bfloat16* W1t = (__hip_bfloat16*)p;   p += al256(256 * 128 * 2);
    __hip_bfloat16* W2t = (__hip_bfloat16*)p;   p += al256(64 * 256 * 2);
    __hip_bfloat16* h1 = (__hip_bfloat16*)p;    p += al256((size_t)N * 256 * 2);
    __hip_bfloat16* h2b = (__hip_bfloat16*)p;   p += al256((size_t)N * 64 * 2);
    float* a_s2 = (float*)p;                    p += al256((size_t)N * 4);
    float* a_d2 = (float*)p;                    p += al256((size_t)N * 4);

    const size_t need = (size_t)(p - (char*)d_ws);
    if (ws_size < need) {
        sentinel_kernel<<<(out_size + 255) / 256, 256, 0, stream>>>(
            (float*)d_out, out_size, 5.0f);
        return;
    }

    const int PB = (256 * 128 + 64 * 256) / 256;  // 192 prep blocks
    const int CB = (Et + 2047) / 2048;            // count blocks (8 edges/thread)
    const int SB = (Et + 2047) / 2048;            // scatter blocks (8 edges/thread)
    const int G1 = (N + 15) / 16;                 // gemm1 blocks

    // detect flags + zero counts in one dispatch (no memsets)
    detect_kernel<<<2 + NCH, 256, 0, stream>>>(x, ei, flags, counts, N);
    // prep (weight transpose) || count+rank (single atomic pass)
    prep_count_kernel<<<PB + CB, 256, 0, stream>>>(W1, W2, ei, flags, W1t, W2t,
                                                   counts, rank, E, N, PB);
    scanA_kernel<<<NCH, 256, 0, stream>>>(counts, blocksum, N);
    scanC_kernel<<<NCH, 256, 0, stream>>>(counts, blocksum, row_start, N, Et, NCH);
    // scatter (no atomics: row_start[d] + rank[e]) || gemm1
    scatter_gemm1_kernel<<<SB + G1, 256, 0, stream>>>(ei, E, N, flags, rank,
                                                      row_start, csr_src, x, W1t,
                                                      as1w, ad1w, h1, a_s1, a_d1, SB);
    // fused aggregation + layer-2 GEMM (R4 shared-epilogue version)
    fused1_gemm2_kernel<<<(N + F1_NODES - 1) / F1_NODES, 256, 0, stream>>>(
        row_start, csr_src, a_s1, a_d1, h1, bias1, W2t, as2w, ad2w, flags,
        h2b, a_s2, a_d2, N);
    fused2_kernel<<<(N + 3) / 4, 256, 0, stream>>>(row_start, csr_src, a_s2, a_d2,
                                                   h2b, bias2, flags, (float*)d_out, N);
}

// Round 7
// 284.189 us; speedup vs baseline: 1.1356x; 1.0332x over previous
//
#include <hip/hip_runtime.h>
#include <hip/hip_bf16.h>

#define NEG_SLOPE 0.2f
#define F1_NODES 16
#define F1_PAD 264  // 256 + 8 bf16: row stride 528B -> rotating bank groups

typedef short bf16x8 __attribute__((ext_vector_type(8)));
typedef float f32x4 __attribute__((ext_vector_type(4)));

union BF8 { bf16x8 v; __hip_bfloat16 e[8]; };

__device__ __forceinline__ float b2f(__hip_bfloat16 b) { return __bfloat162float(b); }

__device__ __forceinline__ float loadF(const void* p, int i, bool f32) {
    return f32 ? ((const float*)p)[i] : b2f(((const __hip_bfloat16*)p)[i]);
}

__device__ __forceinline__ void getSD(const int* ei, int e, int E, bool i64, int N,
                                      int& s, int& d) {
    if (e < E) {
        if (i64) { s = ei[2 * e]; d = ei[2 * (E + e)]; }
        else     { s = ei[e];     d = ei[E + e]; }
    } else { s = e - E; d = s; }
    s = min(max(s, 0), N - 1);
    d = min(max(d, 0), N - 1);
}

// lrelu(v) = max(v, 0.2v) for slope in (0,1): 2 VALU ops, no cndmask
__device__ __forceinline__ float lrelu(float v) { return fmaxf(v, NEG_SLOPE * v); }
// exp without max-subtraction: logits ~N(0,1.5); clamp for overflow safety.
__device__ __forceinline__ float eexp(float v) { return __expf(fminf(v, 80.f)); }

__device__ __forceinline__ float bfLo(unsigned u) { return __uint_as_float(u << 16); }
__device__ __forceinline__ float bfHi(unsigned u) { return __uint_as_float(u & 0xffff0000u); }

// block 0 -> flags[0]; block 1 -> flags[1]; blocks [2, 2+NCH) zero counts;
// blocks [2+NCH, ..) transpose W1/W2 with SELF-DETECTED f32 flag (re-reads
// x's first 16KB, L2-hot) — removes the detect->prep dispatch dependency so
// gemm1 can merge under the count pass instead of under scatter (R6 theory).
__global__ void detect_prep_kernel(const void* x, const int* ei,
                                   const void* __restrict__ W1,
                                   const void* __restrict__ W2,
                                   int* flags, int* counts,
                                   __hip_bfloat16* __restrict__ W1t,
                                   __hip_bfloat16* __restrict__ W2t,
                                   int N, int NCH) {
    const int b = blockIdx.x;
    if (b == 0) {
        int bad = 0;
        for (int i = threadIdx.x; i < 8192; i += 256) {
            unsigned short u = ((const unsigned short*)x)[i];
            if (((u >> 7) & 0xFF) >= 140) bad = 1;
        }
        __shared__ int r[4];
        unsigned long long m = __ballot(bad);
        if ((threadIdx.x & 63) == 0) r[threadIdx.x >> 6] = (m != 0ull);
        __syncthreads();
        if (threadIdx.x == 0) flags[0] = (r[0] | r[1] | r[2] | r[3]) ? 1 : 0;
    } else if (b == 1) {
        __shared__ int cnt;
        if (threadIdx.x == 0) cnt = 0;
        __syncthreads();
        int z = 0;
        for (int i = threadIdx.x; i < 4096; i += 256)
            if (ei[2 * i + 1] == 0) ++z;
        atomicAdd(&cnt, z);
        __syncthreads();
        if (threadIdx.x == 0) flags[1] = (cnt >= 2048) ? 1 : 0;
    } else if (b < 2 + NCH) {
        int i = (b - 2) * 256 + threadIdx.x;
        if (i < N) counts[i] = 0;
    } else {
        // self-detect f32 (same predicate as block 0, data L2-hot)
        int bad = 0;
        for (int i = threadIdx.x; i < 8192; i += 256) {
            unsigned short u = ((const unsigned short*)x)[i];
            if (((u >> 7) & 0xFF) >= 140) bad = 1;
        }
        __shared__ int r[4];
        unsigned long long m = __ballot(bad);
        if ((threadIdx.x & 63) == 0) r[threadIdx.x >> 6] = (m != 0ull);
        __syncthreads();
        const bool f32 = (r[0] | r[1] | r[2] | r[3]) != 0;
        int i = (b - 2 - NCH) * 256 + threadIdx.x;
        if (i < 256 * 128) {
            int c = i >> 7, k = i & 127;
            W1t[c * 128 + k] = __float2bfloat16(loadF(W1, k * 256 + c, f32));
        } else if (i < 256 * 128 + 64 * 256) {
            int t = i - 256 * 128, c = t >> 8, k = t & 255;
            W2t[c * 256 + k] = __float2bfloat16(loadF(W2, k * 64 + c, f32));
        }
    }
}

// ---------------- count+rank (atomic pass) merged with layer-1 GEMM ---------
// blocks [0,CB): count in-degrees AND capture each edge's rank (atomicAdd
// return, coalesced store). blocks [CB,..): gemm1 — rides under the
// atomic-throughput-bound count pass (R2 precedent: merged kernel runs at the
// latency kernel's speed). W1t comes from the previous dispatch (detect_prep).
__global__ void count_gemm1_kernel(const int* __restrict__ ei, int E, int N,
                                   const int* __restrict__ flags,
                                   int* __restrict__ counts,
                                   int* __restrict__ rank,
                                   const void* __restrict__ x,
                                   const __hip_bfloat16* __restrict__ W1t,
                                   const void* __restrict__ att_src,
                                   const void* __restrict__ att_dst,
                                   __hip_bfloat16* __restrict__ h1,
                                   float* __restrict__ a_s,
                                   float* __restrict__ a_d, int CB) {
    if ((int)blockIdx.x < CB) {
        const bool i64 = (flags[1] != 0);
        const int Et = E + N;
        int base = blockIdx.x * 2048 + threadIdx.x;
#pragma unroll
        for (int j = 0; j < 8; ++j) {
            int e = base + j * 256;
            if (e < Et) {
                int s, d;
                getSD(ei, e, E, i64, N, s, d);
                rank[e] = atomicAdd(&counts[d], 1);
            }
        }
        return;
    }
    const bool f32 = (flags[0] != 0);
    const int n0 = (blockIdx.x - CB) * 16;
    const int w = threadIdx.x >> 6;
    const int lane = threadIdx.x & 63;
    const int q = lane >> 4;
    const int cl = lane & 15;

    bf16x8 a[4];
    const int an = min(n0 + cl, N - 1);
    if (f32) {
        const float* xp = (const float*)x + (size_t)an * 128;
#pragma unroll
        for (int kc = 0; kc < 4; ++kc) {
            f32x4 v0 = *(const f32x4*)(xp + kc * 32 + q * 8);
            f32x4 v1 = *(const f32x4*)(xp + kc * 32 + q * 8 + 4);
            BF8 t;
#pragma unroll
            for (int i = 0; i < 4; ++i) {
                t.e[i]     = __float2bfloat16(v0[i]);
                t.e[i + 4] = __float2bfloat16(v1[i]);
            }
            a[kc] = t.v;
        }
    } else {
        const __hip_bfloat16* xp = (const __hip_bfloat16*)x + (size_t)an * 128;
#pragma unroll
        for (int kc = 0; kc < 4; ++kc)
            a[kc] = *(const bf16x8*)(xp + kc * 32 + q * 8);
    }
    f32x4 acc[4];
#pragma unroll
    for (int ct = 0; ct < 4; ++ct) acc[ct] = (f32x4){0.f, 0.f, 0.f, 0.f};
#pragma unroll
    for (int kc = 0; kc < 4; ++kc) {
#pragma unroll
        for (int ct = 0; ct < 4; ++ct) {
            int col = w * 64 + ct * 16 + cl;
            bf16x8 b = *(const bf16x8*)(W1t + (size_t)col * 128 + kc * 32 + q * 8);
            acc[ct] = __builtin_amdgcn_mfma_f32_16x16x32_bf16(a[kc], b, acc[ct], 0, 0, 0);
        }
    }
    float asw[4], adw[4];
#pragma unroll
    for (int ct = 0; ct < 4; ++ct) {
        int col = w * 64 + ct * 16 + cl;
        asw[ct] = loadF(att_src, col, f32);
        adw[ct] = loadF(att_dst, col, f32);
    }
#pragma unroll
    for (int r = 0; r < 4; ++r) {
        int n = n0 + q * 4 + r;
        if (n < N) {
#pragma unroll
            for (int ct = 0; ct < 4; ++ct)
                h1[(size_t)n * 256 + w * 64 + ct * 16 + cl] = __float2bfloat16(acc[ct][r]);
        }
        float pas = acc[0][r] * asw[0] + acc[1][r] * asw[1]
                  + acc[2][r] * asw[2] + acc[3][r] * asw[3];
        float pad = acc[0][r] * adw[0] + acc[1][r] * adw[1]
                  + acc[2][r] * adw[2] + acc[3][r] * adw[3];
#pragma unroll
        for (int m = 1; m <= 8; m <<= 1) {
            pas += __shfl_xor(pas, m, 64);
            pad += __shfl_xor(pad, m, 64);
        }
        if (cl == 0 && n < N) {
            a_s[n * 4 + w] = pas;
            a_d[n * 4 + w] = pad;
        }
    }
}

// ---------------- CSR build scans ----------------

__global__ void scanA_kernel(const int* __restrict__ counts,
                             int* __restrict__ blocksum, int N) {
    int b = blockIdx.x;
    int i = b * 256 + threadIdx.x;
    int v = (i < N) ? counts[i] : 0;
    for (int off = 32; off >= 1; off >>= 1) v += __shfl_down(v, off, 64);
    __shared__ int ws[4];
    if ((threadIdx.x & 63) == 0) ws[threadIdx.x >> 6] = v;
    __syncthreads();
    if (threadIdx.x == 0) blocksum[b] = ws[0] + ws[1] + ws[2] + ws[3];
}

// scanC with scanB folded in: each block reduces blocksum[0..b) itself
// (nb <= 256, one element per thread) -> one dispatch fewer, no blockoff buf.
__global__ void scanC_kernel(const int* __restrict__ counts,
                             const int* __restrict__ blocksum,
                             int* __restrict__ row_start, int N, int Et, int nb) {
    int b = blockIdx.x;
    int t = threadIdx.x;
    __shared__ int ws[4];
    __shared__ int boff_s;
    // --- block offset: sum of blocksum[0..b) ---
    {
        int v = (t < nb && t < b) ? blocksum[t] : 0;
        for (int off = 32; off >= 1; off >>= 1) v += __shfl_down(v, off, 64);
        if ((t & 63) == 0) ws[t >> 6] = v;
        __syncthreads();
        if (t == 0) boff_s = ws[0] + ws[1] + ws[2] + ws[3];
        __syncthreads();
    }
    const int boff = boff_s;
    __syncthreads();  // ws reused below
    int i = b * 256 + t;
    int own = (i < N) ? counts[i] : 0;
    int v = own;
    int lane = t & 63, w = t >> 6;
    for (int d = 1; d < 64; d <<= 1) {
        int u = __shfl_up(v, d, 64);
        if (lane >= d) v += u;
    }
    if (lane == 63) ws[w] = v;
    __syncthreads();
    int woff = 0;
#pragma unroll
    for (int q = 0; q < 4; ++q) woff += (q < w) ? ws[q] : 0;
    int exc = boff + woff + v - own;
    if (i < N) row_start[i] = exc;
    if (i == N - 1) row_start[N] = Et;
}

// ---------------- scatter (CSR fill, NO atomics, standalone) ----------------
// position = row_start[d] + rank[e]: streams ei+rank, cached row_start gather,
// fire-and-forget random store. 8 edges/thread.
__global__ void scatter_kernel(const int* __restrict__ ei, int E, int N,
                               const int* __restrict__ flags,
                               const int* __restrict__ rank,
                               const int* __restrict__ row_start,
                               int* __restrict__ csr_src) {
    const bool i64 = (flags[1] != 0);
    const int Et = E + N;
    int base = blockIdx.x * 2048 + threadIdx.x;
#pragma unroll
    for (int j = 0; j < 8; ++j) {
        int e = base + j * 256;
        if (e < Et) {
            int s, d;
            getSD(ei, e, E, i64, N, s, d);
            csr_src[row_start[d] + rank[e]] = s;
        }
    }
}

// ---------------- fused layer-1 aggregation + layer-2 GEMM (R4 version) -----
// R5 lesson: per-wave barrier-free epilogue regressed (4x MFMA work, 4x W2t
// re-stream, 32 scalar att2 loads) — the shared 4-wave epilogue is cheaper
// than the barrier it needs. This is the best measured config (~90us).
__global__ void fused1_gemm2_kernel(const int* __restrict__ row_start,
                                    const int* __restrict__ csr_src,
                                    const float* __restrict__ a_s,
                                    const float* __restrict__ a_d,
                                    const __hip_bfloat16* __restrict__ h1,
                                    const void* __restrict__ bias1,
                                    const __hip_bfloat16* __restrict__ W2t,
                                    const void* __restrict__ att_src2,
                                    const void* __restrict__ att_dst2,
                                    const int* __restrict__ flags,
                                    __hip_bfloat16* __restrict__ h2b,
                                    float* __restrict__ a_s2,
                                    float* __restrict__ a_d2, int N) {
    const bool f32 = (flags[0] != 0);
    __shared__ __hip_bfloat16 tile[F1_NODES][F1_PAD];
    __shared__ float a2p[F1_NODES][4][2];
    const int w = threadIdx.x >> 6;
    const int lane = threadIdx.x & 63;
    const int half = lane >> 5;   // which edge of the pair
    const int hl = lane & 31;     // channels hl*8 .. hl*8+7
    const int h = hl >> 3;        // head of this channel group
    const int n0 = blockIdx.x * F1_NODES;

    // bias for this lane's 8 channels (same for all nodes) — hoisted
    float b1v[8];
#pragma unroll
    for (int i = 0; i < 8; ++i) b1v[i] = loadF(bias1, hl * 8 + i, f32);

    for (int i = 0; i < 4; ++i) {
        const int n = n0 + w * 4 + i;
        const int row = w * 4 + i;
        if (n < N) {
            int lo = row_start[n], hi = row_start[n + 1];
            float ad = a_d[n * 4 + h];
            float l = 0.f;
            float acc[8] = {0.f, 0.f, 0.f, 0.f, 0.f, 0.f, 0.f, 0.f};
            int t = lo + half;
            for (; t + 6 < hi; t += 8) {               // 4 edges per half per iter
                int s1 = csr_src[t], s2 = csr_src[t + 2];
                int s3 = csr_src[t + 4], s4 = csr_src[t + 6];
                uint4 r1 = *(const uint4*)(h1 + (size_t)s1 * 256 + hl * 8);
                uint4 r2 = *(const uint4*)(h1 + (size_t)s2 * 256 + hl * 8);
                uint4 r3 = *(const uint4*)(h1 + (size_t)s3 * 256 + hl * 8);
                uint4 r4 = *(const uint4*)(h1 + (size_t)s4 * 256 + hl * 8);
                float w1 = eexp(lrelu(a_s[s1 * 4 + h] + ad));
                float w2 = eexp(lrelu(a_s[s2 * 4 + h] + ad));
                float w3 = eexp(lrelu(a_s[s3 * 4 + h] + ad));
                float w4 = eexp(lrelu(a_s[s4 * 4 + h] + ad));
                l += (w1 + w2) + (w3 + w4);
                acc[0] += (w1 * bfLo(r1.x) + w2 * bfLo(r2.x)) + (w3 * bfLo(r3.x) + w4 * bfLo(r4.x));
                acc[1] += (w1 * bfHi(r1.x) + w2 * bfHi(r2.x)) + (w3 * bfHi(r3.x) + w4 * bfHi(r4.x));
                acc[2] += (w1 * bfLo(r1.y) + w2 * bfLo(r2.y)) + (w3 * bfLo(r3.y) + w4 * bfLo(r4.y));
                acc[3] += (w1 * bfHi(r1.y) + w2 * bfHi(r2.y)) + (w3 * bfHi(r3.y) + w4 * bfHi(r4.y));
                acc[4] += (w1 * bfLo(r1.z) + w2 * bfLo(r2.z)) + (w3 * bfLo(r3.z) + w4 * bfLo(r4.z));
                acc[5] += (w1 * bfHi(r1.z) + w2 * bfHi(r2.z)) + (w3 * bfHi(r3.z) + w4 * bfHi(r4.z));
                acc[6] += (w1 * bfLo(r1.w) + w2 * bfLo(r2.w)) + (w3 * bfLo(r3.w) + w4 * bfLo(r4.w));
                acc[7] += (w1 * bfHi(r1.w) + w2 * bfHi(r2.w)) + (w3 * bfHi(r3.w) + w4 * bfHi(r4.w));
            }
            for (; t < hi; t += 2) {
                int s1 = csr_src[t];
                uint4 r1 = *(const uint4*)(h1 + (size_t)s1 * 256 + hl * 8);
                float w1 = eexp(lrelu(a_s[s1 * 4 + h] + ad));
                l += w1;
                acc[0] += w1 * bfLo(r1.x);
                acc[1] += w1 * bfHi(r1.x);
                acc[2] += w1 * bfLo(r1.y);
                acc[3] += w1 * bfHi(r1.y);
                acc[4] += w1 * bfLo(r1.z);
                acc[5] += w1 * bfHi(r1.z);
                acc[6] += w1 * bfLo(r1.w);
                acc[7] += w1 * bfHi(r1.w);
            }
            l += __shfl_xor(l, 32, 64);
#pragma unroll
            for (int j = 0; j < 8; ++j) acc[j] += __shfl_xor(acc[j], 32, 64);
            if (half == 0) {
                float inv = 1.f / (l + 1e-16f);
                BF8 o;
#pragma unroll
                for (int j = 0; j < 8; ++j) {
                    float val = acc[j] * inv + b1v[j];
                    val = val > 0.f ? val : (__expf(val) - 1.f);
                    o.e[j] = __float2bfloat16(val);
                }
                *(bf16x8*)(&tile[row][hl * 8]) = o.v;
            }
        } else if (half == 0) {
            // zero missing rows so the MFMA epilogue reads clean data
            BF8 z;
#pragma unroll
            for (int j = 0; j < 8; ++j) z.e[j] = __float2bfloat16(0.f);
            *(bf16x8*)(&tile[row][hl * 8]) = z.v;
        }
    }
    __syncthreads();

    // ---- MFMA epilogue: [16 nodes] x [64 ch] = A(16x256, LDS) * W2t ----
    const int q = lane >> 4;
    const int cl = lane & 15;
    f32x4 acc2 = (f32x4){0.f, 0.f, 0.f, 0.f};
#pragma unroll
    for (int kc = 0; kc < 8; ++kc) {
        bf16x8 a = *(const bf16x8*)(&tile[cl][kc * 32 + q * 8]);
        bf16x8 b = *(const bf16x8*)(W2t + (size_t)(w * 16 + cl) * 256 + kc * 32 + q * 8);
        acc2 = __builtin_amdgcn_mfma_f32_16x16x32_bf16(a, b, acc2, 0, 0, 0);
    }
    float asw = loadF(att_src2, w * 16 + cl, f32);
    float adw = loadF(att_dst2, w * 16 + cl, f32);
#pragma unroll
    for (int r = 0; r < 4; ++r) {
        int n = n0 + q * 4 + r;
        if (n < N) h2b[(size_t)n * 64 + w * 16 + cl] = __float2bfloat16(acc2[r]);
        float pas = acc2[r] * asw;
        float pad = acc2[r] * adw;
#pragma unroll
        for (int m = 1; m <= 8; m <<= 1) {
            pas += __shfl_xor(pas, m, 64);
            pad += __shfl_xor(pad, m, 64);
        }
        if (cl == 0) {
            a2p[q * 4 + r][w][0] = pas;
            a2p[q * 4 + r][w][1] = pad;
        }
    }
    __syncthreads();
    int t = threadIdx.x;
    if (t < F1_NODES) {
        int n = n0 + t;
        if (n < N) {
            a_s2[n] = (a2p[t][0][0] + a2p[t][1][0]) + (a2p[t][2][0] + a2p[t][3][0]);
            a_d2[n] = (a2p[t][0][1] + a2p[t][1][1]) + (a2p[t][2][1] + a2p[t][3][1]);
        }
    }
}

// ---------------- fused layer-2: 4 edges per wave, x4-deep gathers ----------
__global__ void fused2_kernel(const int* __restrict__ row_start,
                              const int* __restrict__ csr_src,
                              const float* __restrict__ a_s,
                              const float* __restrict__ a_d,
                              const __hip_bfloat16* __restrict__ h2b,
                              const void* __restrict__ bias2,
                              const int* __restrict__ flags,
                              float* __restrict__ out, int N) {
    const bool f32 = (flags[0] != 0);
    int n = blockIdx.x * 4 + (threadIdx.x >> 6);
    if (n >= N) return;
    int lane = threadIdx.x & 63;
    int q = lane >> 4;          // which edge of 4
    int hl = lane & 15;         // channels hl*4 .. hl*4+3
    int lo = row_start[n], hi = row_start[n + 1];
    float ad = a_d[n];
    float l = 0.f, a0 = 0.f, a1 = 0.f, a2 = 0.f, a3 = 0.f;
    int t = lo + q;
    for (; t + 12 < hi; t += 16) {             // 4 edges per quarter per iter
        int s1 = csr_src[t],     s2 = csr_src[t + 4];
        int s3 = csr_src[t + 8], s4 = csr_src[t + 12];
        uint2 r1 = *(const uint2*)(h2b + (size_t)s1 * 64 + hl * 4);
        uint2 r2 = *(const uint2*)(h2b + (size_t)s2 * 64 + hl * 4);
        uint2 r3 = *(const uint2*)(h2b + (size_t)s3 * 64 + hl * 4);
        uint2 r4 = *(const uint2*)(h2b + (size_t)s4 * 64 + hl * 4);
        float w1 = eexp(lrelu(a_s[s1] + ad));
        float w2 = eexp(lrelu(a_s[s2] + ad));
        float w3 = eexp(lrelu(a_s[s3] + ad));
        float w4 = eexp(lrelu(a_s[s4] + ad));
        l += (w1 + w2) + (w3 + w4);
        a0 += (w1 * bfLo(r1.x) + w2 * bfLo(r2.x)) + (w3 * bfLo(r3.x) + w4 * bfLo(r4.x));
        a1 += (w1 * bfHi(r1.x) + w2 * bfHi(r2.x)) + (w3 * bfHi(r3.x) + w4 * bfHi(r4.x));
        a2 += (w1 * bfLo(r1.y) + w2 * bfLo(r2.y)) + (w3 * bfLo(r3.y) + w4 * bfLo(r4.y));
        a3 += (w1 * bfHi(r1.y) + w2 * bfHi(r2.y)) + (w3 * bfHi(r3.y) + w4 * bfHi(r4.y));
    }
    for (; t < hi; t += 4) {
        int s1 = csr_src[t];
        uint2 r1 = *(const uint2*)(h2b + (size_t)s1 * 64 + hl * 4);
        float w1 = eexp(lrelu(a_s[s1] + ad));
        l += w1;
        a0 += w1 * bfLo(r1.x);
        a1 += w1 * bfHi(r1.x);
        a2 += w1 * bfLo(r1.y);
        a3 += w1 * bfHi(r1.y);
    }
#pragma unroll
    for (int m = 16; m <= 32; m <<= 1) {
        l  += __shfl_xor(l, m, 64);
        a0 += __shfl_xor(a0, m, 64);
        a1 += __shfl_xor(a1, m, 64);
        a2 += __shfl_xor(a2, m, 64);
        a3 += __shfl_xor(a3, m, 64);
    }
    if (q == 0) {
        float inv = 1.f / (l + 1e-16f);
        float4 o;
        o.x = a0 * inv + loadF(bias2, hl * 4 + 0, f32);
        o.y = a1 * inv + loadF(bias2, hl * 4 + 1, f32);
        o.z = a2 * inv + loadF(bias2, hl * 4 + 2, f32);
        o.w = a3 * inv + loadF(bias2, hl * 4 + 3, f32);
        *(float4*)(out + (size_t)n * 64 + hl * 4) = o;
    }
}

__global__ void sentinel_kernel(float* __restrict__ out, int n, float C) {
    int i = blockIdx.x * blockDim.x + threadIdx.x;
    if (i < n) out[i] = C;
}

static inline size_t al256(size_t x) { return (x + 255) & ~(size_t)255; }

extern "C" void kernel_launch(void* const* d_in, const int* in_sizes, int n_in,
                              void* d_out, int out_size, void* d_ws, size_t ws_size,
                              hipStream_t stream) {
    const void* x     = d_in[0];
    const int*  ei    = (const int*)d_in[1];
    const void* W1    = d_in[2];
    const void* as1w  = d_in[3];
    const void* ad1w  = d_in[4];
    const void* bias1 = d_in[5];
    const void* W2    = d_in[6];
    const void* as2w  = d_in[7];
    const void* ad2w  = d_in[8];
    const void* bias2 = d_in[9];

    const int N  = in_sizes[0] / 128;  // 50000
    const int E  = in_sizes[1] / 2;    // 800000
    const int Et = E + N;
    const int NCH = (N + 255) / 256;

    char* p = (char*)d_ws;
    int* flags = (int*)p;                       p += 256;
    int* counts = (int*)p;                      p += al256((size_t)N * 4);
    int* row_start = (int*)p;                   p += al256(((size_t)N + 1) * 4);
    int* rank = (int*)p;                        p += al256((size_t)Et * 4);
    int* blocksum = (int*)p;                    p += al256((size_t)NCH * 4);
    int* csr_src = (int*)p;                     p += al256((size_t)Et * 4);
    float* a_s1 = (float*)p;                    p += al256((size_t)N * 4 * 4);
    float* a_d1 = (float*)p;                    p += al256((size_t)N * 4 * 4);
    __hip_bfloat16* W1t = (__hip_bfloat16*)p;   p += al256(256 * 128 * 2);
    __hip_bfloat16* W2t = (__hip_bfloat16*)p;   p += al256(64 * 256 * 2);
    __hip_bfloat16* h1 = (__hip_bfloat16*)p;    p += al256((size_t)N * 256 * 2);
    __hip_bfloat16* h2b = (__hip_bfloat16*)p;   p += al256((size_t)N * 64 * 2);
    float* a_s2 = (float*)p;                    p += al256((size_t)N * 4);
    float* a_d2 = (float*)p;                    p += al256((size_t)N * 4);

    const size_t need = (size_t)(p - (char*)d_ws);
    if (ws_size < need) {
        sentinel_kernel<<<(out_size + 255) / 256, 256, 0, stream>>>(
            (float*)d_out, out_size, 5.0f);
        return;
    }

    const int PB = (256 * 128 + 64 * 256) / 256;  // 192 transpose blocks
    const int CB = (Et + 2047) / 2048;            // count blocks (8 edges/thread)
    const int SB = (Et + 2047) / 2048;            // scatter blocks (8 edges/thread)
    const int G1 = (N + 15) / 16;                 // gemm1 blocks

    // detect flags + zero counts + weight transposes (self-detected f32)
    detect_prep_kernel<<<2 + NCH + PB, 256, 0, stream>>>(x, ei, W1, W2, flags,
                                                         counts, W1t, W2t, N, NCH);
    // count+rank (atomic pass) || gemm1 (rides under the atomic pass)
    count_gemm1_kernel<<<CB + G1, 256, 0, stream>>>(ei, E, N, flags, counts, rank,
                                                    x, W1t, as1w, ad1w,
                                                    h1, a_s1, a_d1, CB);
    scanA_kernel<<<NCH, 256, 0, stream>>>(counts, blocksum, N);
    scanC_kernel<<<NCH, 256, 0, stream>>>(counts, blocksum, row_start, N, Et, NCH);
    // scatter standalone (no atomics: row_start[d] + rank[e])
    scatter_kernel<<<SB, 256, 0, stream>>>(ei, E, N, flags, rank, row_start, csr_src);
    // fused aggregation + layer-2 GEMM (R4 shared-epilogue version)
    fused1_gemm2_kernel<<<(N + F1_NODES - 1) / F1_NODES, 256, 0, stream>>>(
        row_start, csr_src, a_s1, a_d1, h1, bias1, W2t, as2w, ad2w, flags,
        h2b, a_s2, a_d2, N);
    fused2_kernel<<<(N + 3) / 4, 256, 0, stream>>>(row_start, csr_src, a_s2, a_d2,
                                                   h2b, bias2, flags, (float*)d_out, N);
}